// Round 1
// 1655.005 us; speedup vs baseline: 1.0605x; 1.0605x over previous
//
#include <hip/hip_runtime.h>

// Persistent-kernel LSTM: B=128, T=512, D=512, H=512, FORGET_BIAS=1.0
// 128 wgs x 512 thr. wg (mg=wgid&7, hb=wgid>>3): rows 16mg..+16, h-cols
// 32hb..+32, all 4 gates. Wave w: gate g=w&3, col-block jj=w>>2.
// W resident in VGPR/AGPR (32 B-frags/wave). c/h state in registers.
//
// R5: poison-based data polling replaces the {h-store-ack drain -> flag store
// -> flag poll -> data load} chain (3 serial LLC transactions) with ONE:
// consumers poll the h data words themselves. |h|<=1 so a published u32
// (two bf16) can never equal POISON=0xFFFFFFFF. 3-slot rotation, producer
// re-poisons its own chunk of slot t%3 in step-t phase B (safe: it has just
// observed all of h[t+1], which transitively proves every consumer already
// read h[t]; the loop-end __syncthreads vmcnt drain orders the poison ahead
// of that slot's next data write two steps later).
// Intra-step barriers are lgkm-only raw s_barrier (no vmcnt drain) so
// publish/out stores and the x[t+2] prefetch stay in flight across them.
// x staging is split (T14): global->regs issued at phase-A start, regs->LDS
// committed at phase-B end.

#define B_ 128
#define T_ 512
#define D_ 512
#define H_ 512
#define POISON 0xFFFFFFFFu

typedef __bf16 bf16x8 __attribute__((ext_vector_type(8)));
typedef float f32x4 __attribute__((ext_vector_type(4)));
typedef unsigned long long u64;

static __device__ __forceinline__ unsigned short f2bf(float f) {
  return __builtin_bit_cast(unsigned short, (__bf16)f);
}
static __device__ __forceinline__ float fast_sigmoid(float x) {
  return __builtin_amdgcn_rcpf(1.f + __expf(-x));
}
static __device__ __forceinline__ float fast_tanh(float x) {
  float xc = fminf(fmaxf(x, -15.f), 15.f);
  float t = __expf(-2.f * xc);
  return (1.f - t) * __builtin_amdgcn_rcpf(1.f + t);
}
static __device__ __forceinline__ bool clean64(u64 v) {
  return ((unsigned int)v != POISON) && ((unsigned int)(v >> 32) != POISON);
}

// lgkm-only barrier: does NOT drain vmcnt. asm memory clobbers pin LDS/global
// op order on both sides (m194-m201 pattern).
#define LBAR()                                             \
  do {                                                     \
    __asm__ volatile("s_waitcnt lgkmcnt(0)" ::: "memory"); \
    __builtin_amdgcn_s_barrier();                          \
    __asm__ volatile("" ::: "memory");                     \
  } while (0)

// ---- pack W [1024][2048] fp32 -> bf16 B-frag layout (unchanged) ----
// frag f = (hb*8 + w)*32 + kt;  Wp[(f*64+lane)*8 + j] = bf16(W[k][col])
__global__ __launch_bounds__(256) void pack_w_kernel(const float* __restrict__ W,
                                                     unsigned short* __restrict__ Wp) {
  int tid = blockIdx.x * 256 + threadIdx.x;  // [0, 2^21)
  int j = tid & 7;
  int lane = (tid >> 3) & 63;
  int f = tid >> 9;
  int kt = f & 31;
  int w = (f >> 5) & 7;
  int hb = f >> 8;
  int k = (kt << 5) + ((lane >> 4) << 3) + j;
  int col = ((w & 3) << 9) + (hb << 5) + ((w >> 2) << 4) + (lane & 15);
  Wp[tid] = f2bf(W[k * 2048 + col]);
}

__global__ __launch_bounds__(1024) void init_poison_kernel(unsigned int* __restrict__ hg) {
  hg[blockIdx.x * 1024 + threadIdx.x] = POISON;  // 96 x 1024 = 3*8*4096 u32
}

__global__ __launch_bounds__(512, 2) void lstm_persistent(
    const float* __restrict__ wv, const int* __restrict__ nw,
    const float* __restrict__ ic, const float* __restrict__ ih,
    const float* __restrict__ bias, const unsigned short* __restrict__ Wp,
    unsigned int* __restrict__ hg, float* __restrict__ out) {
  __shared__ __align__(16) unsigned short hlds[16 * 512];      // 16 KB
  __shared__ __align__(16) unsigned short xlds[2][16 * 512];   // 32 KB
  __shared__ float zbuf[8][16][17];                            // 8.5 KB (padded)

  const int tid = threadIdx.x;
  const int wgid = blockIdx.x;
  const int mg = wgid & 7;   // row group
  const int hb = wgid >> 3;  // h-col block
  const int w = tid >> 6;    // wave 0..7
  const int lane = tid & 63;
  const int g = w & 3;
  const int jj = w >> 2;

  // elementwise cell: 512 threads <-> 16 rows x 32 h-cols
  const int er = tid >> 5;
  const int ec = tid & 31;
  const int grow = (mg << 4) + er;
  const int gcol = (hb << 5) + ec;

  const int nwv = nw[grow];
  float c_reg = ic[grow * H_ + gcol];
  float h_reg = ih[grow * H_ + gcol];

  // W B-frags: kt 0..15 x-part (rows 0..511), 16..31 h-part
  uint4 wfrag[32];
  {
    const uint4* wp = (const uint4*)Wp + (size_t)((hb * 8 + w) * 32) * 64 + lane;
#pragma unroll
    for (int kt = 0; kt < 32; ++kt) wfrag[kt] = wp[kt * 64];
  }
  const float bv = bias[(g << 9) + (hb << 5) + (jj << 4) + (lane & 15)];

  // 3 rotating h slots; slot s for group mg: 16 KB at hg + (s*8+mg)*4096 u32
  auto slotp = [&](int s) { return hg + (size_t)(s * 8 + mg) * 4096; };

  // h cell slot (bf16 idx): producer hb owns u16 [hb*512, hb*512+512)
  // == k-tile hb of the h A-frag layout (1 KB chunk).
  const int hslot = (hb << 9) + ((er | ((ec >> 3) << 4)) << 3) + (ec & 7);

  auto publish_h = [&](unsigned int* dst) {
    unsigned int hv = (unsigned int)f2bf(h_reg);
    unsigned int up = (unsigned int)__shfl_down((int)hv, 1);
    if ((tid & 1) == 0)
      __hip_atomic_store(dst + (hslot >> 1), hv | (up << 16), __ATOMIC_RELAXED,
                         __HIP_MEMORY_SCOPE_AGENT);
  };

  // Poll-the-data staging: wave w owns producers/k-tiles {2w, 2w+1}.
  // Chunk c = u64 [c*128, c*128+128) of the slot; 2 u64 per lane per chunk.
  // The successful poll iteration IS the data load (single LLC transaction).
  auto wait_stage = [&](const unsigned int* slot) {
    const u64* s = (const u64*)slot;
    const u64* cs0 = s + ((2 * w) << 7);
    const u64* cs1 = s + ((2 * w + 1) << 7);
    u64 a0, a1, b0, b1;
    while (true) {
      a0 = __hip_atomic_load(cs0 + lane, __ATOMIC_RELAXED, __HIP_MEMORY_SCOPE_AGENT);
      a1 = __hip_atomic_load(cs0 + 64 + lane, __ATOMIC_RELAXED, __HIP_MEMORY_SCOPE_AGENT);
      b0 = __hip_atomic_load(cs1 + lane, __ATOMIC_RELAXED, __HIP_MEMORY_SCOPE_AGENT);
      b1 = __hip_atomic_load(cs1 + 64 + lane, __ATOMIC_RELAXED, __HIP_MEMORY_SCOPE_AGENT);
      bool ok = clean64(a0) && clean64(a1) && clean64(b0) && clean64(b1);
      if (__all(ok)) break;
      __builtin_amdgcn_s_sleep(1);
    }
    u64* d = (u64*)hlds;
    d[((2 * w) << 7) + lane] = a0;
    d[((2 * w) << 7) + 64 + lane] = a1;
    d[((2 * w + 1) << 7) + lane] = b0;
    d[((2 * w + 1) << 7) + 64 + lane] = b1;
  };

  auto repoison = [&](unsigned int* slot) {
    if (tid < 256)
      __hip_atomic_store(slot + (hb << 8) + tid, POISON, __ATOMIC_RELAXED,
                         __HIP_MEMORY_SCOPE_AGENT);
  };

  // T14 split x staging: issue global->regs early, commit regs->LDS late.
  float4 xr[4];
  auto xissue = [&](int tt) {
    if (tt >= T_) return;
#pragma unroll
    for (int s2 = 0; s2 < 2; ++s2) {
      int e = tid + (s2 << 9);
      int ktx = e >> 6;
      int le = e & 63;
      int r = le & 15;
      int d = (ktx << 5) + ((le >> 4) << 3);
      const float* src = wv + ((size_t)((mg << 4) + r) * T_ + tt) * D_ + d;
      xr[2 * s2] = *(const float4*)src;
      xr[2 * s2 + 1] = *(const float4*)(src + 4);
    }
  };
  auto xcommit = [&](int buf, int tt) {
    if (tt >= T_) return;
#pragma unroll
    for (int s2 = 0; s2 < 2; ++s2) {
      int e = tid + (s2 << 9);
      int ktx = e >> 6;
      int le = e & 63;
      float4 xa = xr[2 * s2], xb = xr[2 * s2 + 1];
      bf16x8 v;
      v[0] = (__bf16)xa.x; v[1] = (__bf16)xa.y; v[2] = (__bf16)xa.z; v[3] = (__bf16)xa.w;
      v[4] = (__bf16)xb.x; v[5] = (__bf16)xb.y; v[6] = (__bf16)xb.z; v[7] = (__bf16)xb.w;
      *(bf16x8*)&xlds[buf][(ktx << 9) + (le << 3)] = v;
    }
  };

  auto xpart = [&](int buf) {
    f32x4 a = {0.f, 0.f, 0.f, 0.f};
#pragma unroll
    for (int kt = 0; kt < 16; ++kt) {
      bf16x8 af = *(const bf16x8*)&xlds[buf][(kt << 9) + (lane << 3)];
      a = __builtin_amdgcn_mfma_f32_16x16x32_bf16(
          af, __builtin_bit_cast(bf16x8, wfrag[kt]), a, 0, 0, 0);
    }
    return a;
  };

  // ---- prologue: x[0]->buf0, x[1]->buf1, hlds <- bf16(ih) directly ----
  // (no epoch-0 handshake: every wg can read ih itself)
  xissue(0); xcommit(0, 0);
  xissue(1); xcommit(1, 1);
#pragma unroll
  for (int s2 = 0; s2 < 2; ++s2) {
    int e = tid + (s2 << 9);
    int ktx = e >> 6;
    int le = e & 63;
    int r = le & 15;
    int d = (ktx << 5) + ((le >> 4) << 3);
    const float* src = ih + (size_t)((mg << 4) + r) * H_ + d;
    float4 ha = *(const float4*)src;
    float4 hbv = *(const float4*)(src + 4);
    bf16x8 v;
    v[0] = (__bf16)ha.x; v[1] = (__bf16)ha.y; v[2] = (__bf16)ha.z; v[3] = (__bf16)ha.w;
    v[4] = (__bf16)hbv.x; v[5] = (__bf16)hbv.y; v[6] = (__bf16)hbv.z; v[7] = (__bf16)hbv.w;
    *(bf16x8*)&hlds[(ktx << 9) + (le << 3)] = v;
  }
  __syncthreads();
  f32x4 acc = xpart(0);

  for (int t = 0; t < T_; ++t) {
    const int par = t & 1;
    unsigned int* hdst = slotp((t + 1) % 3);  // h[t+1]'s slot

    xissue(t + 2);  // HBM loads fly across the whole step (no vmcnt drain at LBARs)

    // ---- phase A (critical path): h-MFMAs (2 chains), gates, publish ----
    f32x4 acc2 = {0.f, 0.f, 0.f, 0.f};
#pragma unroll
    for (int kt = 0; kt < 8; ++kt) {
      bf16x8 a0 = *(const bf16x8*)&hlds[((2 * kt) << 9) + (lane << 3)];
      bf16x8 a1 = *(const bf16x8*)&hlds[((2 * kt + 1) << 9) + (lane << 3)];
      acc = __builtin_amdgcn_mfma_f32_16x16x32_bf16(
          a0, __builtin_bit_cast(bf16x8, wfrag[16 + 2 * kt]), acc, 0, 0, 0);
      acc2 = __builtin_amdgcn_mfma_f32_16x16x32_bf16(
          a1, __builtin_bit_cast(bf16x8, wfrag[17 + 2 * kt]), acc2, 0, 0, 0);
    }
    {  // C/D layout: col=lane&15, row=(lane>>4)*4+reg
      int q = lane >> 4, cl = lane & 15;
#pragma unroll
      for (int v = 0; v < 4; ++v)
        zbuf[w][q * 4 + v][cl] = acc[v] + acc2[v] + bv;
    }
    LBAR();
    {
      int ej = ec >> 4, ecl = ec & 15;
      float zi = zbuf[ej * 4 + 0][er][ecl];
      float zj = zbuf[ej * 4 + 1][er][ecl];
      float zf = zbuf[ej * 4 + 2][er][ecl];
      float zo = zbuf[ej * 4 + 3][er][ecl];
      float si = fast_sigmoid(zi);
      float sf = fast_sigmoid(zf + 1.f);  // FORGET_BIAS
      float so = fast_sigmoid(zo);
      float tj = fast_tanh(zj);
      float nc = c_reg * sf + si * tj;
      float nh = fast_tanh(nc) * so;
      bool m = t < nwv;
      c_reg = m ? nc : c_reg;
      h_reg = m ? nh : h_reg;
      publish_h(hdst);  // stores fly; consumers poll the data itself
      out[(size_t)t * (B_ * H_) + grow * H_ + gcol] = m ? nh : 0.f;
    }
    LBAR();  // hlds phase-A reads done before phase-B staging writes

    // ---- phase B (overlap): x-part of t+1, stage h[t+1], re-poison, commit x ----
    if (t + 1 < T_) {
      acc = xpart(1 - par);      // x[t+1], committed at t-1
      wait_stage(hdst);          // poll+stage h[t+1] into hlds
      repoison(slotp(t % 3));    // own chunk of h[t]'s slot (reused for h[t+3])
      xcommit(par, t + 2);       // regs -> xlds[par]
    }
    __syncthreads();  // full drain: orders re-poison/publish per-location too
  }

  size_t base = (size_t)T_ * (B_ * H_);
  out[base + grow * H_ + gcol] = c_reg;
  out[base + B_ * H_ + grow * H_ + gcol] = h_reg;
}

extern "C" void kernel_launch(void* const* d_in, const int* in_sizes, int n_in,
                              void* d_out, int out_size, void* d_ws, size_t ws_size,
                              hipStream_t stream) {
  const float* wv = (const float*)d_in[0];    // [B,T,D]
  const int* nw = (const int*)d_in[1];        // [B]
  const float* ic = (const float*)d_in[2];    // [B,H]
  const float* ih = (const float*)d_in[3];    // [B,H]
  const float* W = (const float*)d_in[4];     // [D+H, 4H]
  const float* bias = (const float*)d_in[5];  // [4H]
  float* out = (float*)d_out;

  char* ws = (char*)d_ws;
  unsigned short* Wp = (unsigned short*)ws;             // 4 MB packed W
  unsigned int* hg = (unsigned int*)(ws + (4u << 20));  // 384 KB: 3 slots x 8 groups x 16 KB

  init_poison_kernel<<<96, 1024, 0, stream>>>(hg);
  pack_w_kernel<<<(1 << 21) / 256, 256, 0, stream>>>(W, Wp);
  lstm_persistent<<<128, 512, 0, stream>>>(wv, nw, ic, ih, bias, Wp, hg, out);
}

// Round 4
// 1516.998 us; speedup vs baseline: 1.1570x; 1.0910x over previous
//
#include <hip/hip_runtime.h>

// Persistent-kernel LSTM: B=128, T=512, D=512, H=512, FORGET_BIAS=1.0
// 128 wgs x 512 thr. wg (mg=wgid&7, hb=wgid>>3): rows 16mg..+16, h-cols
// 32hb..+32, all 4 gates. Wave w: gate g=w&3, col-block jj=w>>2.
// W resident in VGPR/AGPR (32 B-frags/wave). c/h state in registers.
//
// R8: revert sc0/XCD experiment (R6/R7 failed correctness) to the PROVEN
// sc1 poison-poll protocol (R5, passed), then remove R5's residual serial
// costs:
//  * 8-slot rotation (1 MB) + lgkm-only step-end barriers, full
//    __syncthreads only every 4th step. The per-step vmcnt(0) drain's only
//    role was poison-completion before republish; republish is now 7 steps
//    away and any 7-step window contains a full drain. Saves the ~600-1000cy
//    poison-flight wait on most steps.
//  * mid-phase-B LBAR kept (R6's race fix): all 8 waves complete wait_stage
//    => all 16 producers published h[t+1] => all wgs finished reading h[t]
//    => poisoning h[t]'s slot is safe for every reader (closes R5's
//    partial-knowledge window where wave w knew only producers 2w,2w+1).
//  * phase A = 4 MFMA accumulator chains of depth 4 (was 2x8); x-part keeps
//    two persistent accumulators (chains of 8) consumed directly by phase A.
//  * xissue moved to phase-B start: its address VALU leaves the critical
//    path; flight still covered (xpart+wait_stage >> HBM latency).
// Fail-fast poll caps kept: protocol failure -> wrong data (passed:false),
// never a hung dispatch.

#define B_ 128
#define T_ 512
#define D_ 512
#define H_ 512
#define POISON 0xFFFFFFFFu
#define POLL_CAP 8192

typedef __bf16 bf16x8 __attribute__((ext_vector_type(8)));
typedef float f32x4 __attribute__((ext_vector_type(4)));
typedef unsigned long long u64;

static __device__ __forceinline__ unsigned short f2bf(float f) {
  return __builtin_bit_cast(unsigned short, (__bf16)f);
}
static __device__ __forceinline__ float fast_sigmoid(float x) {
  return __builtin_amdgcn_rcpf(1.f + __expf(-x));
}
static __device__ __forceinline__ float fast_tanh(float x) {
  float xc = fminf(fmaxf(x, -15.f), 15.f);
  float t = __expf(-2.f * xc);
  return (1.f - t) * __builtin_amdgcn_rcpf(1.f + t);
}
static __device__ __forceinline__ bool clean64(u64 v) {
  return ((unsigned int)v != POISON) && ((unsigned int)(v >> 32) != POISON);
}

// lgkm-only barrier: does NOT drain vmcnt (publish/out/x-prefetch/poison
// stores stay in flight). asm memory clobbers pin op order on both sides.
#define LBAR()                                             \
  do {                                                     \
    __asm__ volatile("s_waitcnt lgkmcnt(0)" ::: "memory"); \
    __builtin_amdgcn_s_barrier();                          \
    __asm__ volatile("" ::: "memory");                     \
  } while (0)

// ---- pack W [1024][2048] fp32 -> bf16 B-frag layout (unchanged) ----
// frag f = (hb*8 + w)*32 + kt;  Wp[(f*64+lane)*8 + j] = bf16(W[k][col])
__global__ __launch_bounds__(256) void pack_w_kernel(const float* __restrict__ W,
                                                     unsigned short* __restrict__ Wp) {
  int tid = blockIdx.x * 256 + threadIdx.x;  // [0, 2^21)
  int j = tid & 7;
  int lane = (tid >> 3) & 63;
  int f = tid >> 9;
  int kt = f & 31;
  int w = (f >> 5) & 7;
  int hb = f >> 8;
  int k = (kt << 5) + ((lane >> 4) << 3) + j;
  int col = ((w & 3) << 9) + (hb << 5) + ((w >> 2) << 4) + (lane & 15);
  Wp[tid] = f2bf(W[k * 2048 + col]);
}

// poison hg: 8 slots x 8 groups x 4096 u32 = 256K u32 = 1 MB
__global__ __launch_bounds__(1024) void init_ws_kernel(unsigned int* __restrict__ hg) {
  hg[blockIdx.x * 1024 + threadIdx.x] = POISON;
}

__global__ __launch_bounds__(512, 2) void lstm_persistent(
    const float* __restrict__ wv, const int* __restrict__ nw,
    const float* __restrict__ ic, const float* __restrict__ ih,
    const float* __restrict__ bias, const unsigned short* __restrict__ Wp,
    unsigned int* __restrict__ hg, float* __restrict__ out) {
  __shared__ __align__(16) unsigned short hlds[16 * 512];      // 16 KB
  __shared__ __align__(16) unsigned short xlds[2][16 * 512];   // 32 KB
  __shared__ float zbuf[8][16][17];                            // 8.5 KB (padded)

  const int tid = threadIdx.x;
  const int wgid = blockIdx.x;
  const int mg = wgid & 7;   // row group
  const int hb = wgid >> 3;  // h-col block
  const int w = tid >> 6;    // wave 0..7
  const int lane = tid & 63;
  const int g = w & 3;
  const int jj = w >> 2;

  // elementwise cell: 512 threads <-> 16 rows x 32 h-cols
  const int er = tid >> 5;
  const int ec = tid & 31;
  const int grow = (mg << 4) + er;
  const int gcol = (hb << 5) + ec;

  const int nwv = nw[grow];
  float c_reg = ic[grow * H_ + gcol];
  float h_reg = ih[grow * H_ + gcol];

  // W B-frags: kt 0..15 x-part (rows 0..511), 16..31 h-part
  uint4 wfrag[32];
  {
    const uint4* wp = (const uint4*)Wp + (size_t)((hb * 8 + w) * 32) * 64 + lane;
#pragma unroll
    for (int kt = 0; kt < 32; ++kt) wfrag[kt] = wp[kt * 64];
  }
  const float bv = bias[(g << 9) + (hb << 5) + (jj << 4) + (lane & 15)];

  // 8 rotating h slots; slot s for group mg: 16 KB at hg + (s*8+mg)*4096 u32
  auto slotp = [&](int s) { return hg + (size_t)(s * 8 + mg) * 4096; };

  // h cell slot (bf16 idx): producer hb owns u16 [hb*512, hb*512+512)
  // == k-tile hb of the h A-frag layout (1 KB chunk).
  const int hslot = (hb << 9) + ((er | ((ec >> 3) << 4)) << 3) + (ec & 7);

  auto publish_h = [&](unsigned int* dst) {
    unsigned int hv = (unsigned int)f2bf(h_reg);
    unsigned int up = (unsigned int)__shfl_down((int)hv, 1);
    if ((tid & 1) == 0)
      __hip_atomic_store(dst + (hslot >> 1), hv | (up << 16), __ATOMIC_RELAXED,
                         __HIP_MEMORY_SCOPE_AGENT);
  };

  // Poll-the-data staging: wave w owns producers/k-tiles {2w, 2w+1}.
  // Iteration-capped: a broken protocol terminates with wrong data
  // (clean passed:false diagnostic) instead of hanging the dispatch.
  auto wait_stage = [&](const unsigned int* slot) {
    const u64* s = (const u64*)slot;
    const u64* p0 = s + ((2 * w) << 7) + lane;
    const u64* p1 = p0 + 64;
    const u64* p2 = s + ((2 * w + 1) << 7) + lane;
    const u64* p3 = p2 + 64;
    u64 a0, a1, b0, b1;
    int it = 0;
    while (true) {
      a0 = __hip_atomic_load(p0, __ATOMIC_RELAXED, __HIP_MEMORY_SCOPE_AGENT);
      a1 = __hip_atomic_load(p1, __ATOMIC_RELAXED, __HIP_MEMORY_SCOPE_AGENT);
      b0 = __hip_atomic_load(p2, __ATOMIC_RELAXED, __HIP_MEMORY_SCOPE_AGENT);
      b1 = __hip_atomic_load(p3, __ATOMIC_RELAXED, __HIP_MEMORY_SCOPE_AGENT);
      if (__all(clean64(a0) && clean64(a1) && clean64(b0) && clean64(b1))) break;
      if (++it > POLL_CAP) break;
      if (it > 8) __builtin_amdgcn_s_sleep(1);  // busy-poll first; then be nice
    }
    u64* d = (u64*)hlds;
    d[((2 * w) << 7) + lane] = a0;
    d[((2 * w) << 7) + 64 + lane] = a1;
    d[((2 * w + 1) << 7) + lane] = b0;
    d[((2 * w + 1) << 7) + 64 + lane] = b1;
  };

  auto repoison = [&](unsigned int* slot) {
    if (tid < 256)
      __hip_atomic_store(slot + (hb << 8) + tid, POISON, __ATOMIC_RELAXED,
                         __HIP_MEMORY_SCOPE_AGENT);
  };

  // T14 split x staging: issue global->regs in phase B (poll-slack window),
  // commit regs->LDS at phase-B end.
  float4 xr[4];
  auto xissue = [&](int tt) {
    if (tt >= T_) return;
#pragma unroll
    for (int s2 = 0; s2 < 2; ++s2) {
      int e = tid + (s2 << 9);
      int ktx = e >> 6;
      int le = e & 63;
      int r = le & 15;
      int d = (ktx << 5) + ((le >> 4) << 3);
      const float* src = wv + ((size_t)((mg << 4) + r) * T_ + tt) * D_ + d;
      xr[2 * s2] = *(const float4*)src;
      xr[2 * s2 + 1] = *(const float4*)(src + 4);
    }
  };
  auto xcommit = [&](int buf, int tt) {
    if (tt >= T_) return;
#pragma unroll
    for (int s2 = 0; s2 < 2; ++s2) {
      int e = tid + (s2 << 9);
      int ktx = e >> 6;
      int le = e & 63;
      float4 xa = xr[2 * s2], xb = xr[2 * s2 + 1];
      bf16x8 v;
      v[0] = (__bf16)xa.x; v[1] = (__bf16)xa.y; v[2] = (__bf16)xa.z; v[3] = (__bf16)xa.w;
      v[4] = (__bf16)xb.x; v[5] = (__bf16)xb.y; v[6] = (__bf16)xb.z; v[7] = (__bf16)xb.w;
      *(bf16x8*)&xlds[buf][(ktx << 9) + (le << 3)] = v;
    }
  };

  // x-part: two persistent accumulator chains (depth 8 each), consumed
  // directly by phase A's 4-chain reduction.
  f32x4 xA, xB;
  auto xpart = [&](int buf) {
    f32x4 A = {0.f, 0.f, 0.f, 0.f};
    f32x4 Bc = {0.f, 0.f, 0.f, 0.f};
#pragma unroll
    for (int kt = 0; kt < 8; ++kt) {
      bf16x8 a0 = *(const bf16x8*)&xlds[buf][(kt << 9) + (lane << 3)];
      bf16x8 a1 = *(const bf16x8*)&xlds[buf][((kt + 8) << 9) + (lane << 3)];
      A = __builtin_amdgcn_mfma_f32_16x16x32_bf16(
          a0, __builtin_bit_cast(bf16x8, wfrag[kt]), A, 0, 0, 0);
      Bc = __builtin_amdgcn_mfma_f32_16x16x32_bf16(
          a1, __builtin_bit_cast(bf16x8, wfrag[kt + 8]), Bc, 0, 0, 0);
    }
    xA = A;
    xB = Bc;
  };

  // ---- prologue: x[0]->buf0, x[1]->buf1, hlds <- bf16(ih) directly ----
  // (no epoch-0 handshake: every wg reads ih itself)
  xissue(0); xcommit(0, 0);
  xissue(1); xcommit(1, 1);
#pragma unroll
  for (int s2 = 0; s2 < 2; ++s2) {
    int e = tid + (s2 << 9);
    int ktx = e >> 6;
    int le = e & 63;
    int r = le & 15;
    int d = (ktx << 5) + ((le >> 4) << 3);
    const float* src = ih + (size_t)((mg << 4) + r) * H_ + d;
    float4 ha = *(const float4*)src;
    float4 hbv = *(const float4*)(src + 4);
    bf16x8 v;
    v[0] = (__bf16)ha.x; v[1] = (__bf16)ha.y; v[2] = (__bf16)ha.z; v[3] = (__bf16)ha.w;
    v[4] = (__bf16)hbv.x; v[5] = (__bf16)hbv.y; v[6] = (__bf16)hbv.z; v[7] = (__bf16)hbv.w;
    *(bf16x8*)&hlds[(ktx << 9) + (le << 3)] = v;
  }
  __syncthreads();
  xpart(0);

  for (int t = 0; t < T_; ++t) {
    const int par = t & 1;
    unsigned int* hdst = slotp((t + 1) & 7);  // h[t+1]'s slot

    // ---- phase A (critical path): h-MFMAs (4 chains of 4), gates, publish ----
    f32x4 c0 = xA, c1 = xB;
    f32x4 c2 = {0.f, 0.f, 0.f, 0.f};
    f32x4 c3 = {0.f, 0.f, 0.f, 0.f};
#pragma unroll
    for (int i = 0; i < 4; ++i) {
      bf16x8 a0 = *(const bf16x8*)&hlds[((4 * i) << 9) + (lane << 3)];
      bf16x8 a1 = *(const bf16x8*)&hlds[((4 * i + 1) << 9) + (lane << 3)];
      bf16x8 a2 = *(const bf16x8*)&hlds[((4 * i + 2) << 9) + (lane << 3)];
      bf16x8 a3 = *(const bf16x8*)&hlds[((4 * i + 3) << 9) + (lane << 3)];
      c0 = __builtin_amdgcn_mfma_f32_16x16x32_bf16(
          a0, __builtin_bit_cast(bf16x8, wfrag[16 + 4 * i]), c0, 0, 0, 0);
      c1 = __builtin_amdgcn_mfma_f32_16x16x32_bf16(
          a1, __builtin_bit_cast(bf16x8, wfrag[17 + 4 * i]), c1, 0, 0, 0);
      c2 = __builtin_amdgcn_mfma_f32_16x16x32_bf16(
          a2, __builtin_bit_cast(bf16x8, wfrag[18 + 4 * i]), c2, 0, 0, 0);
      c3 = __builtin_amdgcn_mfma_f32_16x16x32_bf16(
          a3, __builtin_bit_cast(bf16x8, wfrag[19 + 4 * i]), c3, 0, 0, 0);
    }
    {  // C/D layout: col=lane&15, row=(lane>>4)*4+reg
      int q = lane >> 4, cl = lane & 15;
#pragma unroll
      for (int v = 0; v < 4; ++v)
        zbuf[w][q * 4 + v][cl] = (c0[v] + c1[v]) + (c2[v] + c3[v]) + bv;
    }
    LBAR();
    {
      int ej = ec >> 4, ecl = ec & 15;
      float zi = zbuf[ej * 4 + 0][er][ecl];
      float zj = zbuf[ej * 4 + 1][er][ecl];
      float zf = zbuf[ej * 4 + 2][er][ecl];
      float zo = zbuf[ej * 4 + 3][er][ecl];
      float si = fast_sigmoid(zi);
      float sf = fast_sigmoid(zf + 1.f);  // FORGET_BIAS
      float so = fast_sigmoid(zo);
      float tj = fast_tanh(zj);
      float nc = c_reg * sf + si * tj;
      float nh = fast_tanh(nc) * so;
      bool m = t < nwv;
      c_reg = m ? nc : c_reg;
      h_reg = m ? nh : h_reg;
      publish_h(hdst);  // first store after gates: minimal publish latency
      out[(size_t)t * (B_ * H_) + grow * H_ + gcol] = m ? nh : 0.f;
    }
    // (no barrier here: phase-A hlds reads all precede the zbuf LBAR, so
    //  phase-B staging writes cannot race them)

    // ---- phase B (overlap): x-prefetch, x-part of t+1, stage h[t+1],
    //      re-poison, commit x ----
    if (t + 1 < T_) {
      xissue(t + 2);             // HBM loads fly under xpart+wait_stage
      xpart(1 - par);            // x[t+1], committed at t-1
      wait_stage(hdst);          // poll+stage h[t+1] into hlds
      LBAR();                    // ALL waves staged h[t+1] => all 16 wgs
                                 // published h[t+1] => all finished reading
                                 // h[t] => poisoning h[t]'s slot is safe
      repoison(slotp(t & 7));    // slot of h[t]; republished at step t+7
      xcommit(par, t + 2);       // regs -> xlds[par]
    }
    // step-end barrier: lgkm-only, except a full vmcnt drain every 4th step
    // (orders each poison ahead of its slot's republish 7 steps later).
    if ((t & 3) == 3) __syncthreads(); else LBAR();
  }

  size_t base = (size_t)T_ * (B_ * H_);
  out[base + grow * H_ + gcol] = c_reg;
  out[base + B_ * H_ + grow * H_ + gcol] = h_reg;
}

extern "C" void kernel_launch(void* const* d_in, const int* in_sizes, int n_in,
                              void* d_out, int out_size, void* d_ws, size_t ws_size,
                              hipStream_t stream) {
  const float* wv = (const float*)d_in[0];    // [B,T,D]
  const int* nw = (const int*)d_in[1];        // [B]
  const float* ic = (const float*)d_in[2];    // [B,H]
  const float* ih = (const float*)d_in[3];    // [B,H]
  const float* W = (const float*)d_in[4];     // [D+H, 4H]
  const float* bias = (const float*)d_in[5];  // [4H]
  float* out = (float*)d_out;

  char* ws = (char*)d_ws;
  unsigned short* Wp = (unsigned short*)ws;             // 4 MB packed W
  unsigned int* hg = (unsigned int*)(ws + (4u << 20));  // 1 MB: 8 slots x 8 groups x 16 KB

  init_ws_kernel<<<256, 1024, 0, stream>>>(hg);
  pack_w_kernel<<<(1 << 21) / 256, 256, 0, stream>>>(W, Wp);
  lstm_persistent<<<128, 512, 0, stream>>>(wv, nw, ic, ih, bias, Wp, hg, out);
}